// Round 2
// baseline (5099.747 us; speedup 1.0000x reference)
//
#include <hip/hip_runtime.h>
#include <math.h>

// GIN on MI355X. N=100000, E=1600000, H=F=64, C=10, diameter=6 (fixed).
// R2: register-blocked GEMM (W in 64 VGPRs, t via LDS broadcast b128 reads),
// 8 nodes/wave, edge loop unrolled x4 for load ILP. fp32 throughout.

#define NPW 8  // nodes per wave; block = 4 waves = 32 nodes

// ---------- small utility kernels ----------
__global__ void zero_i32(int* __restrict__ p, int n) {
    int i = blockIdx.x * blockDim.x + threadIdx.x;
    if (i < n) p[i] = 0;
}

__global__ void count_deg(const int* __restrict__ dst, int E, int* __restrict__ deg) {
    int i = blockIdx.x * blockDim.x + threadIdx.x;
    if (i < E) atomicAdd(&deg[dst[i]], 1);
}

// inclusive scan within 256-element chunks
__global__ void scan1(const int* __restrict__ deg, int n,
                      int* __restrict__ incl, int* __restrict__ chunkSum) {
    __shared__ int s[256];
    int c = blockIdx.x;
    int i = c * 256 + threadIdx.x;
    int v = (i < n) ? deg[i] : 0;
    s[threadIdx.x] = v;
    __syncthreads();
    for (int off = 1; off < 256; off <<= 1) {
        int t = (threadIdx.x >= (unsigned)off) ? s[threadIdx.x - off] : 0;
        __syncthreads();
        s[threadIdx.x] += t;
        __syncthreads();
    }
    if (i < n) incl[i] = s[threadIdx.x];
    if (threadIdx.x == 255) chunkSum[c] = s[255];
}

// exclusive scan of chunk sums (nchunks <= 1024), in place
__global__ void scan2(int* __restrict__ chunkSum, int nchunks) {
    __shared__ int s[1024];
    int v = (threadIdx.x < (unsigned)nchunks) ? chunkSum[threadIdx.x] : 0;
    s[threadIdx.x] = v;
    __syncthreads();
    for (int off = 1; off < 1024; off <<= 1) {
        int t = (threadIdx.x >= (unsigned)off) ? s[threadIdx.x - off] : 0;
        __syncthreads();
        s[threadIdx.x] += t;
        __syncthreads();
    }
    if (threadIdx.x < (unsigned)nchunks) chunkSum[threadIdx.x] = s[threadIdx.x] - v;
}

// incl (in-place) -> exclusive rowstart; also init cursor
__global__ void scan3(int* __restrict__ incl_to_rowstart, const int* __restrict__ deg,
                      const int* __restrict__ chunkOff, int n, int* __restrict__ cursor) {
    int i = blockIdx.x * blockDim.x + threadIdx.x;
    if (i < n) {
        int rs = incl_to_rowstart[i] - deg[i] + chunkOff[i >> 8];
        incl_to_rowstart[i] = rs;
        cursor[i] = rs;
    }
}

__global__ void scatter_edges(const int* __restrict__ src, const int* __restrict__ dst, int E,
                              int* __restrict__ cursor, int* __restrict__ csr_src) {
    int i = blockIdx.x * blockDim.x + threadIdx.x;
    if (i < E) {
        int pos = atomicAdd(&cursor[dst[i]], 1);
        csr_src[pos] = src[i];
    }
}

// ---------- encoder: h = x @ enc_w + enc_b, 8 nodes/wave, reg-blocked GEMM ----------
__global__ __launch_bounds__(256, 4) void encode_k(const float* __restrict__ x,
                                                   const float* __restrict__ w,
                                                   const float* __restrict__ b,
                                                   float* __restrict__ h, int n) {
    __shared__ float hs[4][NPW][64];
    int wv = threadIdx.x >> 6;
    int lane = threadIdx.x & 63;
    int base = (blockIdx.x * 4 + wv) * NPW;

    // stage input rows into wave-private LDS tile
#pragma unroll
    for (int r = 0; r < NPW; r++) {
        int node = base + r;
        if (node < n) hs[wv][r][lane] = x[(size_t)node * 64 + lane];
    }

    // W column `lane` into registers (coalesced 256B per k)
    float wreg[64];
#pragma unroll
    for (int k = 0; k < 64; k++) wreg[k] = w[k * 64 + lane];
    float bias = b[lane];

    float acc[NPW];
#pragma unroll
    for (int r = 0; r < NPW; r++) acc[r] = bias;
#pragma unroll
    for (int kc = 0; kc < 16; kc++) {
#pragma unroll
        for (int r = 0; r < NPW; r++) {
            float4 h4 = *(const float4*)&hs[wv][r][kc * 4];  // broadcast b128
            acc[r] = fmaf(h4.x, wreg[kc * 4 + 0], acc[r]);
            acc[r] = fmaf(h4.y, wreg[kc * 4 + 1], acc[r]);
            acc[r] = fmaf(h4.z, wreg[kc * 4 + 2], acc[r]);
            acc[r] = fmaf(h4.w, wreg[kc * 4 + 3], acc[r]);
        }
    }
#pragma unroll
    for (int r = 0; r < NPW; r++) {
        int node = base + r;
        if (node < n) h[(size_t)node * 64 + lane] = acc[r];
    }
}

// ---------- GIN step: agg = max over in-edges; h' = (h+agg)@W + b ----------
__global__ __launch_bounds__(256, 4) void gin_step_k(const float* __restrict__ hin,
                                                     float* __restrict__ hout,
                                                     const int* __restrict__ rowstart,
                                                     const int* __restrict__ rowend,
                                                     const int* __restrict__ csr_src,
                                                     const float* __restrict__ w,
                                                     const float* __restrict__ b, int n) {
    __shared__ float hs[4][NPW][64];
    int wv = threadIdx.x >> 6;
    int lane = threadIdx.x & 63;
    int base = (blockIdx.x * 4 + wv) * NPW;

    // phase 1: gather (max over in-edges), unrolled x4 for load ILP
    for (int r = 0; r < NPW; r++) {
        int node = base + r;
        if (node >= n) break;
        int e0 = rowstart[node];
        int e1 = rowend[node];
        float hv = hin[(size_t)node * 64 + lane];
        float m = -INFINITY;
        int e = e0;
        for (; e + 4 <= e1; e += 4) {
            int s0 = csr_src[e];
            int s1 = csr_src[e + 1];
            int s2 = csr_src[e + 2];
            int s3 = csr_src[e + 3];
            float a0 = hin[(size_t)s0 * 64 + lane];
            float a1 = hin[(size_t)s1 * 64 + lane];
            float a2 = hin[(size_t)s2 * 64 + lane];
            float a3 = hin[(size_t)s3 * 64 + lane];
            m = fmaxf(m, fmaxf(fmaxf(a0, a1), fmaxf(a2, a3)));
        }
        for (; e < e1; e++) m = fmaxf(m, hin[(size_t)csr_src[e] * 64 + lane]);
        float agg = (e0 < e1) ? m : 0.0f;  // empty segment -> 0 (isfinite fixup)
        hs[wv][r][lane] = hv + agg;
    }

    // W column `lane` into registers
    float wreg[64];
#pragma unroll
    for (int k = 0; k < 64; k++) wreg[k] = w[k * 64 + lane];
    float bias = b[lane];

    // phase 2: reg-blocked GEMM, t rows via broadcast ds_read_b128
    float acc[NPW];
#pragma unroll
    for (int r = 0; r < NPW; r++) acc[r] = bias;
#pragma unroll
    for (int kc = 0; kc < 16; kc++) {
#pragma unroll
        for (int r = 0; r < NPW; r++) {
            float4 h4 = *(const float4*)&hs[wv][r][kc * 4];
            acc[r] = fmaf(h4.x, wreg[kc * 4 + 0], acc[r]);
            acc[r] = fmaf(h4.y, wreg[kc * 4 + 1], acc[r]);
            acc[r] = fmaf(h4.z, wreg[kc * 4 + 2], acc[r]);
            acc[r] = fmaf(h4.w, wreg[kc * 4 + 3], acc[r]);
        }
    }
#pragma unroll
    for (int r = 0; r < NPW; r++) {
        int node = base + r;
        if (node < n) hout[(size_t)node * 64 + lane] = acc[r];
    }
}

// ---------- decoder: log_softmax(h @ dec_w + dec_b), wave-per-node ----------
__global__ __launch_bounds__(256) void decode_k(const float* __restrict__ h,
                                                const float* __restrict__ w,
                                                const float* __restrict__ b,
                                                float* __restrict__ out, int n) {
    int wv = threadIdx.x >> 6;
    int lane = threadIdx.x & 63;
    int node = blockIdx.x * 4 + wv;
    if (node >= n) return;
    float hv = h[(size_t)node * 64 + lane];
    float l[10];
#pragma unroll
    for (int c = 0; c < 10; c++) l[c] = hv * w[lane * 10 + c];
#pragma unroll
    for (int off = 32; off >= 1; off >>= 1) {
#pragma unroll
        for (int c = 0; c < 10; c++) l[c] += __shfl_down(l[c], off);
    }
    if (lane == 0) {
        float mx = -INFINITY;
#pragma unroll
        for (int c = 0; c < 10; c++) { l[c] += b[c]; mx = fmaxf(mx, l[c]); }
        float sum = 0.0f;
#pragma unroll
        for (int c = 0; c < 10; c++) sum += expf(l[c] - mx);
        float lse = mx + logf(sum);
#pragma unroll
        for (int c = 0; c < 10; c++) out[(size_t)node * 10 + c] = l[c] - lse;
    }
}

extern "C" void kernel_launch(void* const* d_in, const int* in_sizes, int n_in,
                              void* d_out, int out_size, void* d_ws, size_t ws_size,
                              hipStream_t stream) {
    const float* x     = (const float*)d_in[0];
    const int*   ei    = (const int*)d_in[1];
    // d_in[2] = diameter (always 6; loop count must be static for graph capture)
    const float* enc_w = (const float*)d_in[3];
    const float* enc_b = (const float*)d_in[4];
    const float* proc_w = (const float*)d_in[5];
    const float* proc_b = (const float*)d_in[6];
    const float* dec_w = (const float*)d_in[7];
    const float* dec_b = (const float*)d_in[8];
    float* out = (float*)d_out;

    const int n = in_sizes[0] / 64;
    const int E = in_sizes[1] / 2;
    const int* src = ei;
    const int* dst = ei + E;

    // workspace carve (ws re-poisoned every call -> rebuild everything)
    char* p = (char*)d_ws;
    float* h_a = (float*)p;          p += (size_t)n * 64 * sizeof(float);
    float* h_b = (float*)p;          p += (size_t)n * 64 * sizeof(float);
    int* deg   = (int*)p;            p += (size_t)n * sizeof(int);
    int* rs    = (int*)p;            p += (size_t)n * sizeof(int);   // incl -> rowstart
    int* cur   = (int*)p;            p += (size_t)n * sizeof(int);   // cursor -> rowend
    int* chunk = (int*)p;            p += 1024 * sizeof(int);
    int* csr   = (int*)p;            p += (size_t)E * sizeof(int);

    const int nchunks = (n + 255) / 256;
    const int gN = (n + 255) / 256;
    const int gE = (E + 255) / 256;
    const int gTile = (n + 4 * NPW - 1) / (4 * NPW);
    const int gNode = (n + 3) / 4;

    // CSR build
    zero_i32<<<gN, 256, 0, stream>>>(deg, n);
    count_deg<<<gE, 256, 0, stream>>>(dst, E, deg);
    scan1<<<nchunks, 256, 0, stream>>>(deg, n, rs, chunk);
    scan2<<<1, 1024, 0, stream>>>(chunk, nchunks);
    scan3<<<gN, 256, 0, stream>>>(rs, deg, chunk, n, cur);
    scatter_edges<<<gE, 256, 0, stream>>>(src, dst, E, cur, csr);

    // encoder
    encode_k<<<gTile, 256, 0, stream>>>(x, enc_w, enc_b, h_a, n);

    // 6 GIN steps, ping-pong h_a <-> h_b
    float* hi = h_a;
    float* ho = h_b;
    for (int it = 0; it < 6; it++) {
        gin_step_k<<<gTile, 256, 0, stream>>>(hi, ho, rs, cur, csr, proc_w, proc_b, n);
        float* tmp = hi; hi = ho; ho = tmp;
    }

    // decoder (+ log_softmax)
    decode_k<<<gNode, 256, 0, stream>>>(hi, dec_w, dec_b, out, n);
}

// Round 3
// 908.263 us; speedup vs baseline: 5.6148x; 5.6148x over previous
//
#include <hip/hip_runtime.h>
#include <math.h>

// GIN on MI355X. N=100000, E=1600000, H=F=64, C=10, diameter=6 (fixed).
// R3: fix R2's scratch-spill disaster. W lives in LDS (16KB/block); GEMM
// consumes W in 8-register chunks (unroll 1 -> compiler cannot rebuild the
// 64-deep array that spilled in R2). t rows staged in LDS, read back as
// wave-uniform broadcast float4. Gather unchanged (x4 unrolled). fp32.

#define NPW 8  // nodes per wave; block = 4 waves = 32 nodes

// ---------- small utility kernels ----------
__global__ void zero_i32(int* __restrict__ p, int n) {
    int i = blockIdx.x * blockDim.x + threadIdx.x;
    if (i < n) p[i] = 0;
}

__global__ void count_deg(const int* __restrict__ dst, int E, int* __restrict__ deg) {
    int i = blockIdx.x * blockDim.x + threadIdx.x;
    if (i < E) atomicAdd(&deg[dst[i]], 1);
}

// inclusive scan within 256-element chunks
__global__ void scan1(const int* __restrict__ deg, int n,
                      int* __restrict__ incl, int* __restrict__ chunkSum) {
    __shared__ int s[256];
    int c = blockIdx.x;
    int i = c * 256 + threadIdx.x;
    int v = (i < n) ? deg[i] : 0;
    s[threadIdx.x] = v;
    __syncthreads();
    for (int off = 1; off < 256; off <<= 1) {
        int t = (threadIdx.x >= (unsigned)off) ? s[threadIdx.x - off] : 0;
        __syncthreads();
        s[threadIdx.x] += t;
        __syncthreads();
    }
    if (i < n) incl[i] = s[threadIdx.x];
    if (threadIdx.x == 255) chunkSum[c] = s[255];
}

// exclusive scan of chunk sums (nchunks <= 1024), in place
__global__ void scan2(int* __restrict__ chunkSum, int nchunks) {
    __shared__ int s[1024];
    int v = (threadIdx.x < (unsigned)nchunks) ? chunkSum[threadIdx.x] : 0;
    s[threadIdx.x] = v;
    __syncthreads();
    for (int off = 1; off < 1024; off <<= 1) {
        int t = (threadIdx.x >= (unsigned)off) ? s[threadIdx.x - off] : 0;
        __syncthreads();
        s[threadIdx.x] += t;
        __syncthreads();
    }
    if (threadIdx.x < (unsigned)nchunks) chunkSum[threadIdx.x] = s[threadIdx.x] - v;
}

// incl (in-place) -> exclusive rowstart; also init cursor
__global__ void scan3(int* __restrict__ incl_to_rowstart, const int* __restrict__ deg,
                      const int* __restrict__ chunkOff, int n, int* __restrict__ cursor) {
    int i = blockIdx.x * blockDim.x + threadIdx.x;
    if (i < n) {
        int rs = incl_to_rowstart[i] - deg[i] + chunkOff[i >> 8];
        incl_to_rowstart[i] = rs;
        cursor[i] = rs;
    }
}

__global__ void scatter_edges(const int* __restrict__ src, const int* __restrict__ dst, int E,
                              int* __restrict__ cursor, int* __restrict__ csr_src) {
    int i = blockIdx.x * blockDim.x + threadIdx.x;
    if (i < E) {
        int pos = atomicAdd(&cursor[dst[i]], 1);
        csr_src[pos] = src[i];
    }
}

// ---------- shared GEMM epilogue: acc[r] = bias + hs_row_r . W ----------
// W in LDS as Ws[k*64 + col] (bank = lane%32 -> 2-way aliasing, free).
// Chunked: 8 k-values per chunk, wreg[8] only -> no spill.
__device__ __forceinline__ void gemm8(const float* __restrict__ Ws,
                                      const float (*hsw)[64],  // [NPW][64]
                                      float bias, int lane, float acc[NPW]) {
#pragma unroll
    for (int r = 0; r < NPW; r++) acc[r] = bias;
#pragma unroll 1
    for (int kc = 0; kc < 8; kc++) {
        float wreg[8];
#pragma unroll
        for (int j = 0; j < 8; j++) wreg[j] = Ws[(kc * 8 + j) * 64 + lane];
#pragma unroll
        for (int r = 0; r < NPW; r++) {
            float4 a = *(const float4*)&hsw[r][kc * 8];      // broadcast b128
            float4 c = *(const float4*)&hsw[r][kc * 8 + 4];  // broadcast b128
            acc[r] = fmaf(a.x, wreg[0], acc[r]);
            acc[r] = fmaf(a.y, wreg[1], acc[r]);
            acc[r] = fmaf(a.z, wreg[2], acc[r]);
            acc[r] = fmaf(a.w, wreg[3], acc[r]);
            acc[r] = fmaf(c.x, wreg[4], acc[r]);
            acc[r] = fmaf(c.y, wreg[5], acc[r]);
            acc[r] = fmaf(c.z, wreg[6], acc[r]);
            acc[r] = fmaf(c.w, wreg[7], acc[r]);
        }
    }
}

// ---------- encoder: h = x @ enc_w + enc_b ----------
__global__ __launch_bounds__(256, 4) void encode_k(const float* __restrict__ x,
                                                   const float* __restrict__ w,
                                                   const float* __restrict__ b,
                                                   float* __restrict__ h, int n) {
    __shared__ float Ws[64 * 64];
    __shared__ float hs[4][NPW][64];
    {
        const float4* w4 = (const float4*)w;
        float4* s4 = (float4*)Ws;
        for (int i = threadIdx.x; i < 1024; i += 256) s4[i] = w4[i];
    }
    int wv = threadIdx.x >> 6;
    int lane = threadIdx.x & 63;
    int base = (blockIdx.x * 4 + wv) * NPW;

#pragma unroll
    for (int r = 0; r < NPW; r++) {
        int node = base + r;
        if (node < n) hs[wv][r][lane] = x[(size_t)node * 64 + lane];
    }
    __syncthreads();

    float bias = b[lane];
    float acc[NPW];
    gemm8(Ws, hs[wv], bias, lane, acc);

#pragma unroll
    for (int r = 0; r < NPW; r++) {
        int node = base + r;
        if (node < n) h[(size_t)node * 64 + lane] = acc[r];
    }
}

// ---------- GIN step: agg = max over in-edges; h' = (h+agg)@W + b ----------
__global__ __launch_bounds__(256, 4) void gin_step_k(const float* __restrict__ hin,
                                                     float* __restrict__ hout,
                                                     const int* __restrict__ rowstart,
                                                     const int* __restrict__ rowend,
                                                     const int* __restrict__ csr_src,
                                                     const float* __restrict__ w,
                                                     const float* __restrict__ b, int n) {
    __shared__ float Ws[64 * 64];
    __shared__ float hs[4][NPW][64];
    {
        const float4* w4 = (const float4*)w;
        float4* s4 = (float4*)Ws;
        for (int i = threadIdx.x; i < 1024; i += 256) s4[i] = w4[i];
    }
    int wv = threadIdx.x >> 6;
    int lane = threadIdx.x & 63;
    int base = (blockIdx.x * 4 + wv) * NPW;

    // phase 1: gather (max over in-edges), unrolled x4 for load ILP
    for (int r = 0; r < NPW; r++) {
        int node = base + r;
        if (node >= n) break;
        int e0 = rowstart[node];
        int e1 = rowend[node];
        float hv = hin[(size_t)node * 64 + lane];
        float m = -INFINITY;
        int e = e0;
        for (; e + 4 <= e1; e += 4) {
            int s0 = csr_src[e];
            int s1 = csr_src[e + 1];
            int s2 = csr_src[e + 2];
            int s3 = csr_src[e + 3];
            float a0 = hin[(size_t)s0 * 64 + lane];
            float a1 = hin[(size_t)s1 * 64 + lane];
            float a2 = hin[(size_t)s2 * 64 + lane];
            float a3 = hin[(size_t)s3 * 64 + lane];
            m = fmaxf(m, fmaxf(fmaxf(a0, a1), fmaxf(a2, a3)));
        }
        for (; e < e1; e++) m = fmaxf(m, hin[(size_t)csr_src[e] * 64 + lane]);
        float agg = (e0 < e1) ? m : 0.0f;  // empty segment -> 0 (isfinite fixup)
        hs[wv][r][lane] = hv + agg;
    }
    __syncthreads();  // Ws ready (hs is wave-private, but Ws is block-shared)

    float bias = b[lane];
    float acc[NPW];
    gemm8(Ws, hs[wv], bias, lane, acc);

#pragma unroll
    for (int r = 0; r < NPW; r++) {
        int node = base + r;
        if (node < n) hout[(size_t)node * 64 + lane] = acc[r];
    }
}

// ---------- decoder: log_softmax(h @ dec_w + dec_b), wave-per-node ----------
__global__ __launch_bounds__(256) void decode_k(const float* __restrict__ h,
                                                const float* __restrict__ w,
                                                const float* __restrict__ b,
                                                float* __restrict__ out, int n) {
    int wv = threadIdx.x >> 6;
    int lane = threadIdx.x & 63;
    int node = blockIdx.x * 4 + wv;
    if (node >= n) return;
    float hv = h[(size_t)node * 64 + lane];
    float l[10];
#pragma unroll
    for (int c = 0; c < 10; c++) l[c] = hv * w[lane * 10 + c];
#pragma unroll
    for (int off = 32; off >= 1; off >>= 1) {
#pragma unroll
        for (int c = 0; c < 10; c++) l[c] += __shfl_down(l[c], off);
    }
    if (lane == 0) {
        float mx = -INFINITY;
#pragma unroll
        for (int c = 0; c < 10; c++) { l[c] += b[c]; mx = fmaxf(mx, l[c]); }
        float sum = 0.0f;
#pragma unroll
        for (int c = 0; c < 10; c++) sum += expf(l[c] - mx);
        float lse = mx + logf(sum);
#pragma unroll
        for (int c = 0; c < 10; c++) out[(size_t)node * 10 + c] = l[c] - lse;
    }
}

extern "C" void kernel_launch(void* const* d_in, const int* in_sizes, int n_in,
                              void* d_out, int out_size, void* d_ws, size_t ws_size,
                              hipStream_t stream) {
    const float* x     = (const float*)d_in[0];
    const int*   ei    = (const int*)d_in[1];
    // d_in[2] = diameter (always 6; loop count must be static for graph capture)
    const float* enc_w = (const float*)d_in[3];
    const float* enc_b = (const float*)d_in[4];
    const float* proc_w = (const float*)d_in[5];
    const float* proc_b = (const float*)d_in[6];
    const float* dec_w = (const float*)d_in[7];
    const float* dec_b = (const float*)d_in[8];
    float* out = (float*)d_out;

    const int n = in_sizes[0] / 64;
    const int E = in_sizes[1] / 2;
    const int* src = ei;
    const int* dst = ei + E;

    // workspace carve (ws re-poisoned every call -> rebuild everything)
    char* p = (char*)d_ws;
    float* h_a = (float*)p;          p += (size_t)n * 64 * sizeof(float);
    float* h_b = (float*)p;          p += (size_t)n * 64 * sizeof(float);
    int* deg   = (int*)p;            p += (size_t)n * sizeof(int);
    int* rs    = (int*)p;            p += (size_t)n * sizeof(int);   // incl -> rowstart
    int* cur   = (int*)p;            p += (size_t)n * sizeof(int);   // cursor -> rowend
    int* chunk = (int*)p;            p += 1024 * sizeof(int);
    int* csr   = (int*)p;            p += (size_t)E * sizeof(int);

    const int nchunks = (n + 255) / 256;
    const int gN = (n + 255) / 256;
    const int gE = (E + 255) / 256;
    const int gTile = (n + 4 * NPW - 1) / (4 * NPW);
    const int gNode = (n + 3) / 4;

    // CSR build
    zero_i32<<<gN, 256, 0, stream>>>(deg, n);
    count_deg<<<gE, 256, 0, stream>>>(dst, E, deg);
    scan1<<<nchunks, 256, 0, stream>>>(deg, n, rs, chunk);
    scan2<<<1, 1024, 0, stream>>>(chunk, nchunks);
    scan3<<<gN, 256, 0, stream>>>(rs, deg, chunk, n, cur);
    scatter_edges<<<gE, 256, 0, stream>>>(src, dst, E, cur, csr);

    // encoder
    encode_k<<<gTile, 256, 0, stream>>>(x, enc_w, enc_b, h_a, n);

    // 6 GIN steps, ping-pong h_a <-> h_b
    float* hi = h_a;
    float* ho = h_b;
    for (int it = 0; it < 6; it++) {
        gin_step_k<<<gTile, 256, 0, stream>>>(hi, ho, rs, cur, csr, proc_w, proc_b, n);
        float* tmp = hi; hi = ho; ho = tmp;
    }

    // decoder (+ log_softmax)
    decode_k<<<gNode, 256, 0, stream>>>(hi, dec_w, dec_b, out, n);
}